// Round 5
// baseline (147.434 us; speedup 1.0000x reference)
//
#include <hip/hip_runtime.h>

// Density-Aware Chamfer Loss, B=8, N=M=4096, fp32.
// Round 5: full dedup with round-4 discipline. One 128x128 tile-pair per
// block; row AND col accumulators in registers; single end-of-block flush.
//   cross:   1 enumeration, dual mins: 6 slots / 2 outputs (atomicMin, exact)
//   density: upper-triangle, symmetric:   10 slots / 2 outputs (atomicAdd)

#define NPTS 4096
#define NB   8
#define TS   128
#define TPB  256
#define BIGF 3.4e38f

#define NT         32                 // tiles per cloud
#define NPAIR_TRI  528                // NT*(NT+1)/2
#define DENS_BLKS  (NPAIR_TRI * 16)   // 8448: 2 clouds x 8 batches
#define CROSS_BLKS (NB * NT * NT)     // 8192

// unpack 8 consecutive xyz points (6 float4) from LDS into register arrays
__device__ __forceinline__ void unpack8(const float4* s4, int base,
                                        float (&X)[8], float (&Y)[8], float (&Z)[8])
{
    float4 A = s4[base+0], B = s4[base+1], C = s4[base+2];
    float4 D = s4[base+3], E = s4[base+4], F = s4[base+5];
    X[0]=A.x; Y[0]=A.y; Z[0]=A.z;  X[1]=A.w; Y[1]=B.x; Z[1]=B.y;
    X[2]=B.z; Y[2]=B.w; Z[2]=C.x;  X[3]=C.y; Y[3]=C.z; Z[3]=C.w;
    X[4]=D.x; Y[4]=D.y; Z[4]=D.z;  X[5]=D.w; Y[5]=E.x; Z[5]=E.y;
    X[6]=E.z; Y[6]=E.w; Z[6]=F.x;  X[7]=F.y; Y[7]=F.z; Z[7]=F.w;
}

__global__ __launch_bounds__(256) void dacl_init(int* __restrict__ mins,
                                                 float* __restrict__ dens)
{
    const int g = blockIdx.x * 256 + threadIdx.x;   // [0, 65536)
    mins[g] = 0x7F800000;                            // +inf bits
    dens[g] = 0.0f;
}

__global__ __launch_bounds__(TPB) void dacl_pairs(
    const float* __restrict__ pred, const float* __restrict__ gt,
    const float* __restrict__ bwp,  const float* __restrict__ bwg,
    int*   __restrict__ minP2G, int*   __restrict__ minG2P,
    float* __restrict__ densP,  float* __restrict__ densG)
{
    __shared__ float4 sA[96], sB[96];   // 1.5 KB each
    __shared__ float  sRed[384];        // cross-wave reduction scratch

    const int tid  = threadIdx.x;
    const int ty   = tid & 15;      // row octet (lane bits 0..3)
    const int tx   = tid >> 4;      // col octet (lane bits 4..5 + wave)
    const int wave = tid >> 6;
    const int lane = tid & 63;
    const int bid  = blockIdx.x;

    if (bid < DENS_BLKS) {
        // ================= density: symmetric tile-pair (I<=J) ===============
        int pi = bid % NPAIR_TRI;
        const int cb = bid / NPAIR_TRI;     // [0,16)
        const int b  = cb & 7;
        const int cl = cb >> 3;
        int I = 0;
        while (pi >= NT - I) { pi -= NT - I; ++I; }
        const int J = I + pi;

        const float* __restrict__ P = cl ? gt : pred;
        float* __restrict__ D = cl ? densG : densP;
        const float bw = cl ? bwg[0] : bwp[0];
        const float sc = sqrtf(0.5f / (bw*bw*0.6931471805599453f)); // exp2 prescale

        const float4* tA = (const float4*)(P + ((size_t)b*NPTS + I*TS)*3);
        const float4* tB = (const float4*)(P + ((size_t)b*NPTS + J*TS)*3);
        if (tid < 96) {
            float4 v = tA[tid];
            v.x*=sc; v.y*=sc; v.z*=sc; v.w*=sc;  sA[tid] = v;
        } else if (tid >= 128 && tid < 224) {
            const int i = tid - 128;
            float4 v = tB[i];
            v.x*=sc; v.y*=sc; v.z*=sc; v.w*=sc;  sB[i] = v;
        }
        __syncthreads();

        float rx[8], ry[8], rz[8], nrr[8], racc[8];
        unpack8(sA, ty*6, rx, ry, rz);
        #pragma unroll
        for (int r = 0; r < 8; ++r) {
            nrr[r]  = -fmaf(rx[r],rx[r], fmaf(ry[r],ry[r], rz[r]*rz[r]));
            racc[r] = 0.0f;
        }
        float cx[8], cy[8], cz[8];
        unpack8(sB, tx*6, cx, cy, cz);

        if (I == J) {
            // diagonal tile: row accumulation covers everything (self incl.)
            #pragma unroll
            for (int c = 0; c < 8; ++c) {
                const float ax = 2.0f*cx[c], ay = 2.0f*cy[c], az = 2.0f*cz[c];
                const float ncc = fmaf(-cx[c],cx[c], fmaf(-cy[c],cy[c], -cz[c]*cz[c]));
                #pragma unroll
                for (int r = 0; r < 8; ++r) {
                    float e = fmaf(ax, rx[r], ncc);
                    e = fmaf(ay, ry[r], e);
                    e = fmaf(az, rz[r], e);
                    racc[r] += __builtin_amdgcn_exp2f(e + nrr[r]);
                }
            }
        } else {
            float cacc[8];
            #pragma unroll
            for (int c = 0; c < 8; ++c) cacc[c] = 0.0f;
            #pragma unroll
            for (int c = 0; c < 8; ++c) {
                const float ax = 2.0f*cx[c], ay = 2.0f*cy[c], az = 2.0f*cz[c];
                const float ncc = fmaf(-cx[c],cx[c], fmaf(-cy[c],cy[c], -cz[c]*cz[c]));
                #pragma unroll
                for (int r = 0; r < 8; ++r) {
                    float e = fmaf(ax, rx[r], ncc);
                    e = fmaf(ay, ry[r], e);
                    e = fmaf(az, rz[r], e);
                    const float k = __builtin_amdgcn_exp2f(e + nrr[r]);
                    racc[r] += k;
                    cacc[c] += k;
                }
            }
            // col flush: in-wave complete (cols partitioned by wave), once
            #pragma unroll
            for (int c = 0; c < 8; ++c) {
                float v = cacc[c];
                v += __shfl_xor(v, 1, 64);
                v += __shfl_xor(v, 2, 64);
                v += __shfl_xor(v, 4, 64);
                v += __shfl_xor(v, 8, 64);
                if (ty == 0)
                    atomicAdd(&D[b*NPTS + J*TS + tx*8 + c], v);
            }
        }
        // row flush: partial over in-wave tx, LDS across waves, one atomic
        float vv[8];
        #pragma unroll
        for (int r = 0; r < 8; ++r) {
            float v = racc[r];
            v += __shfl_xor(v, 16, 64);
            v += __shfl_xor(v, 32, 64);
            vv[r] = v;
        }
        if (wave > 0 && lane < 16) {
            #pragma unroll
            for (int r = 0; r < 8; ++r) sRed[(wave-1)*128 + lane*8 + r] = vv[r];
        }
        __syncthreads();
        if (wave == 0 && lane < 16) {
            #pragma unroll
            for (int r = 0; r < 8; ++r) {
                const int o = lane*8 + r;
                atomicAdd(&D[b*NPTS + I*TS + o],
                          (vv[r] + sRed[o]) + (sRed[128+o] + sRed[256+o]));
            }
        }
    } else {
        // ================= cross: tile-pair (pred I) x (gt J), dual mins =====
        const int cb   = bid - DENS_BLKS;
        const int b    = cb >> 10;
        const int rest = cb & 1023;
        const int I    = rest >> 5;
        const int J    = rest & 31;

        const float4* tA = (const float4*)(pred + ((size_t)b*NPTS + I*TS)*3);
        const float4* tB = (const float4*)(gt   + ((size_t)b*NPTS + J*TS)*3);
        if (tid < 96) sA[tid] = tA[tid];
        else if (tid >= 128 && tid < 224) sB[tid-128] = tB[tid-128];
        __syncthreads();

        float rx[8], ry[8], rz[8], rr[8], rmin[8], cmin[8];
        unpack8(sA, ty*6, rx, ry, rz);
        #pragma unroll
        for (int r = 0; r < 8; ++r) {
            rr[r]   = fmaf(rx[r],rx[r], fmaf(ry[r],ry[r], rz[r]*rz[r]));
            rmin[r] = BIGF;
        }
        float cx[8], cy[8], cz[8];
        unpack8(sB, tx*6, cx, cy, cz);
        #pragma unroll
        for (int c = 0; c < 8; ++c) cmin[c] = BIGF;

        #pragma unroll
        for (int c = 0; c < 8; ++c) {
            const float ax = -2.0f*cx[c], ay = -2.0f*cy[c], az = -2.0f*cz[c];
            const float cc = fmaf(cx[c],cx[c], fmaf(cy[c],cy[c], cz[c]*cz[c]));
            #pragma unroll
            for (int r = 0; r < 8; ++r) {
                float t = fmaf(ax, rx[r], cc);
                t = fmaf(ay, ry[r], t);
                t = fmaf(az, rz[r], t);
                rmin[r] = fminf(rmin[r], t);          // min(cc - 2rc), +rr later
                cmin[c] = fminf(cmin[c], t + rr[r]);  // true d^2
            }
        }
        // G->P mins: in-wave complete, clamp>=0 -> bitwise-exact atomicMin
        #pragma unroll
        for (int c = 0; c < 8; ++c) {
            float v = fmaxf(cmin[c], 0.0f);
            v = fminf(v, __shfl_xor(v, 1, 64));
            v = fminf(v, __shfl_xor(v, 2, 64));
            v = fminf(v, __shfl_xor(v, 4, 64));
            v = fminf(v, __shfl_xor(v, 8, 64));
            if (ty == 0)
                atomicMin(&minG2P[b*NPTS + J*TS + tx*8 + c], __float_as_int(v));
        }
        // P->G mins
        float vv[8];
        #pragma unroll
        for (int r = 0; r < 8; ++r) {
            float v = fmaxf(rmin[r] + rr[r], 0.0f);
            v = fminf(v, __shfl_xor(v, 16, 64));
            v = fminf(v, __shfl_xor(v, 32, 64));
            vv[r] = v;
        }
        if (wave > 0 && lane < 16) {
            #pragma unroll
            for (int r = 0; r < 8; ++r) sRed[(wave-1)*128 + lane*8 + r] = vv[r];
        }
        __syncthreads();
        if (wave == 0 && lane < 16) {
            #pragma unroll
            for (int r = 0; r < 8; ++r) {
                const int o = lane*8 + r;
                const float m = fminf(fminf(vv[r], sRed[o]),
                                      fminf(sRed[128+o], sRed[256+o]));
                atomicMin(&minP2G[b*NPTS + I*TS + o], __float_as_int(m));
            }
        }
    }
}

__global__ __launch_bounds__(256) void dacl_combine(
    const int* __restrict__ minP2G, const int* __restrict__ minG2P,
    const float* __restrict__ densP, const float* __restrict__ densG,
    float* __restrict__ bsum)
{
    const int g   = blockIdx.x * 256 + threadIdx.x;  // [0, 65536)
    const int dir = g >> 15;
    const int idx = g & 32767;
    const float m  = __int_as_float(dir ? minG2P[idx] : minP2G[idx]);
    const float dn =                 dir ? densG[idx]  : densP[idx];
    float val = m / (dn * (1.0f/4095.0f) + 1e-6f) * (1.0f/32768.0f);

    #pragma unroll
    for (int off = 32; off; off >>= 1) val += __shfl_down(val, off);
    __shared__ float sm[4];
    const int lane = threadIdx.x & 63, wid = threadIdx.x >> 6;
    if (lane == 0) sm[wid] = val;
    __syncthreads();
    if (threadIdx.x == 0) bsum[blockIdx.x] = (sm[0] + sm[1]) + (sm[2] + sm[3]);
}

__global__ __launch_bounds__(256) void dacl_final(
    const float* __restrict__ bsum, float* __restrict__ out)
{
    float v = bsum[threadIdx.x];
    #pragma unroll
    for (int off = 32; off; off >>= 1) v += __shfl_down(v, off);
    __shared__ float sm[4];
    const int lane = threadIdx.x & 63, wid = threadIdx.x >> 6;
    if (lane == 0) sm[wid] = v;
    __syncthreads();
    if (threadIdx.x == 0) out[0] = (sm[0] + sm[1]) + (sm[2] + sm[3]);
}

extern "C" void kernel_launch(void* const* d_in, const int* in_sizes, int n_in,
                              void* d_out, int out_size, void* d_ws, size_t ws_size,
                              hipStream_t stream)
{
    const float* pred = (const float*)d_in[0];
    const float* gt   = (const float*)d_in[1];
    const float* bwp  = (const float*)d_in[2];
    const float* bwg  = (const float*)d_in[3];

    int*   minP2G = (int*)d_ws;                   // [NB*NPTS]
    int*   minG2P = minP2G + NB*NPTS;             // [NB*NPTS]
    float* densP  = (float*)(minG2P + NB*NPTS);   // [NB*NPTS]
    float* densG  = densP + NB*NPTS;              // [NB*NPTS]
    float* bsum   = densG + NB*NPTS;              // [256]

    dacl_init<<<(2*NB*NPTS)/256, 256, 0, stream>>>(minP2G, densP);
    dacl_pairs<<<DENS_BLKS + CROSS_BLKS, TPB, 0, stream>>>(
        pred, gt, bwp, bwg, minP2G, minG2P, densP, densG);
    dacl_combine<<<(2*NB*NPTS)/256, 256, 0, stream>>>(minP2G, minG2P, densP, densG, bsum);
    dacl_final<<<1, 256, 0, stream>>>(bsum, (float*)d_out);
}